// Round 9
// baseline (1196.006 us; speedup 1.0000x reference)
//
#include <hip/hip_runtime.h>
#include <hip/hip_bf16.h>
#include <math.h>

#define DD 64
#define HIDC 128
#define FN 92
#define FE 41
#define S2CAP 192
#define NPB 32      // nodes per fused-conv block
#define ECAP 320    // edge capacity per chunk (mean 205 for 32 nodes; chunk loop covers overflow)

typedef unsigned short u16;
typedef short bf16x8 __attribute__((ext_vector_type(8)));
typedef float f32x4 __attribute__((ext_vector_type(4)));
typedef u16 u16x8 __attribute__((ext_vector_type(8)));

__device__ __forceinline__ float sigmoidf_(float x){ return 1.f/(1.f+expf(-x)); }

__device__ __forceinline__ u16 f2bf(float v){
  union { float f; unsigned u; } x; x.f = v;
  unsigned r = x.u + 0x7fff + ((x.u >> 16) & 1);
  return (u16)(r >> 16);
}
__device__ __forceinline__ float bf2f(u16 v){
  union { float f; unsigned u; } x; x.u = ((unsigned)v) << 16;
  return x.f;
}
__device__ __forceinline__ void split_bf(float v, u16& h, u16& l){
  h = f2bf(v); l = f2bf(v - bf2f(h));
}

// ---------------- pack/transpose small weights ----------------
__global__ void k_pack(const float* __restrict__ lin0_w, const float* __restrict__ nn1_w,
                       const float* __restrict__ root_w, const float* __restrict__ gwih,
                       const float* __restrict__ gwhh, const float* __restrict__ lwih,
                       const float* __restrict__ lwhh, const float* __restrict__ lin1_w,
                       float* __restrict__ lin0T, float* __restrict__ nn1T,
                       float* __restrict__ rootT, float* __restrict__ wihT,
                       float* __restrict__ whhT, float* __restrict__ lwihT,
                       float* __restrict__ lwhhT, float* __restrict__ lin1T)
{
  int idx = blockIdx.x*blockDim.x + threadIdx.x;
  if (idx < 92*64){ int k=idx/64, o=idx%64; lin0T[k*64+o] = lin0_w[o*92+k]; return; } idx -= 92*64;
  if (idx < 41*128){ int k=idx/128, h=idx%128; nn1T[k*128+h] = nn1_w[h*41+k]; return; } idx -= 41*128;
  if (idx < 64*64){ int i=idx/64, o=idx%64; rootT[i*64+o] = root_w[o*64+i]; return; } idx -= 64*64;
  if (idx < 64*192){ int i=idx/192, g=idx%192; wihT[i*192+g] = gwih[g*64+i]; return; } idx -= 64*192;
  if (idx < 64*192){ int i=idx/192, g=idx%192; whhT[i*192+g] = gwhh[g*64+i]; return; } idx -= 64*192;
  if (idx < 128*256){ int j=idx/256, t=idx%256; lwihT[j*256+t] = lwih[t*128+j]; return; } idx -= 128*256;
  if (idx < 64*256){ int j=idx/256, t=idx%256; lwhhT[j*256+t] = lwhh[t*64+j]; return; } idx -= 64*256;
  if (idx < 128*64){ int j=idx/64, t=idx%64; lin1T[j*64+t] = lin1_w[t*128+j]; return; }
}

// Split nn2_w into bf16 hi/lo, transposed for MFMA B-fragments:
// BT[c*262144 + (h*64+o)*64 + i] = nn2_w[(i*64+o)*128 + c*64 + h]   (c = 64-h chunk)
__global__ void k_pack_b2(const float* __restrict__ nn2_w,
                          u16* __restrict__ BhT, u16* __restrict__ BlT){
  int idx = blockIdx.x*256 + threadIdx.x;
  if (idx >= 524288) return;
  int i  = idx & 63;
  int ho = (idx >> 6) & 4095;
  int c  = idx >> 18;
  int h = ho >> 6, o = ho & 63;
  float v = nn2_w[(size_t)(i*64+o)*128 + c*64 + h];
  u16 hi, lo; split_bf(v, hi, lo);
  BhT[idx] = hi; BlT[idx] = lo;
}

// nn1_w [128,41] -> B-fragment layout [h][k] padded K=64, bf16 hi/lo
__global__ void k_pack_b1(const float* __restrict__ nn1_w,
                          u16* __restrict__ BT1h, u16* __restrict__ BT1l){
  int idx = blockIdx.x*256 + threadIdx.x;
  if (idx >= 8192) return;
  int h = idx >> 6, k = idx & 63;
  float v = (k < FE) ? nn1_w[(size_t)h*FE + k] : 0.f;
  u16 hi, lo; split_bf(v, hi, lo);
  BT1h[idx] = hi; BT1l[idx] = lo;
}

// gather ea rows into sorted order, split bf16 hi/lo, pad K 41->64
__global__ void k_split_ea(const float* __restrict__ ea, const int* __restrict__ sortedE,
                           u16* __restrict__ eaH, u16* __restrict__ eaL, int E){
  int idx = blockIdx.x*256 + threadIdx.x;
  if (idx >= E*64) return;
  int ew = idx >> 6, k = idx & 63;
  int e = sortedE[ew];
  float v = (k < FE) ? ea[(size_t)e*FE + k] : 0.f;
  u16 hi, lo; split_bf(v, hi, lo);
  eaH[idx] = hi; eaL[idx] = lo;
}

// ---------------- node MLP: 4 nodes/thread (weight loads amortized 4x) ----------
__global__ __launch_bounds__(256) void k_node_mlp(const float* __restrict__ x,
    const float* __restrict__ lin0T, const float* __restrict__ lin0_b,
    const float* __restrict__ nn2_b,
    float* __restrict__ out, u16* __restrict__ outH, u16* __restrict__ outL,
    float* __restrict__ bterm, int N)
{
  __shared__ float xs[16][FN];
  const int w = threadIdx.x>>6, o = threadIdx.x&63;
  const int nb = blockIdx.x*16 + w*4;
  for (int idx = o; idx < 4*FN; idx += 64){
    int j = idx/FN, k = idx%FN;
    int n = nb + j;
    xs[w*4+j][k] = (n<N) ? x[(size_t)n*FN + k] : 0.f;
  }
  // per-wave LDS slice: in-wave lgkmcnt ordering, no barrier
  float acc[4];
  float bv = lin0_b[o];
  #pragma unroll
  for (int j=0;j<4;j++) acc[j] = bv;
  for (int k=0;k<FN;k++){
    float lw = lin0T[k*64+o];
    #pragma unroll
    for (int j=0;j<4;j++) acc[j] = fmaf(xs[w*4+j][k], lw, acc[j]);
  }
  float v[4];
  #pragma unroll
  for (int j=0;j<4;j++){
    v[j] = fmaxf(acc[j], 0.f);
    int n = nb + j;
    if (n < N){
      out[(size_t)n*64+o] = v[j];
      u16 hi, lo; split_bf(v[j], hi, lo);
      outH[(size_t)n*64+o] = hi;
      outL[(size_t)n*64+o] = lo;
    }
  }
  float bt[4] = {0.f,0.f,0.f,0.f};
  for (int i=0;i<64;i++){
    float wnb = nn2_b[i*64+o];
    #pragma unroll
    for (int j=0;j<4;j++) bt[j] = fmaf(__shfl(v[j], i, 64), wnb, bt[j]);
  }
  #pragma unroll
  for (int j=0;j<4;j++){
    int n = nb + j;
    if (n < N) bterm[(size_t)n*64+o] = bt[j];
  }
}

// ---------------- degree + src histogram ----------------
__global__ void k_count(const int* __restrict__ dst, const int* __restrict__ src,
                        float* __restrict__ deg, int* __restrict__ scnt, int E){
  int e = blockIdx.x*blockDim.x + threadIdx.x;
  if (e < E){
    atomicAdd(&deg[dst[e]], 1.f);
    atomicAdd(&scnt[src[e]], 1);
  }
}

// ---------------- 3-kernel exclusive scan over scnt[N] ----------------
__global__ void k_scan1(const int* __restrict__ cnt, int* __restrict__ excl,
                        int* __restrict__ bsum, int N){
  __shared__ int buf[256];
  int i = blockIdx.x*256 + threadIdx.x;
  int v = (i<N) ? cnt[i] : 0;
  buf[threadIdx.x] = v;
  __syncthreads();
  #pragma unroll
  for (int off=1; off<256; off<<=1){
    int t = (threadIdx.x>=off) ? buf[threadIdx.x-off] : 0;
    __syncthreads();
    buf[threadIdx.x] += t;
    __syncthreads();
  }
  if (i<N) excl[i] = buf[threadIdx.x] - v;
  if (threadIdx.x==255) bsum[blockIdx.x] = buf[255];
}
__global__ void k_scan2(int* __restrict__ bsum, int nb){
  __shared__ int buf[256];
  int v = (threadIdx.x<nb) ? bsum[threadIdx.x] : 0;
  buf[threadIdx.x] = v;
  __syncthreads();
  #pragma unroll
  for (int off=1; off<256; off<<=1){
    int t = (threadIdx.x>=off) ? buf[threadIdx.x-off] : 0;
    __syncthreads();
    buf[threadIdx.x] += t;
    __syncthreads();
  }
  if (threadIdx.x<nb) bsum[threadIdx.x] = buf[threadIdx.x] - v;
}
__global__ void k_scan3(int* __restrict__ starts, int* __restrict__ cursor,
                        const int* __restrict__ bsum, int N, int E){
  int i = blockIdx.x*256 + threadIdx.x;
  if (i<N){
    int s = starts[i] + bsum[blockIdx.x];
    starts[i] = s;
    cursor[i] = s;
  }
  if (i==0) starts[N] = E;
}

// ---------------- scatter: sortedE grouped by src, + sorted dst array -------
__global__ void k_sort(const int* __restrict__ src, const int* __restrict__ dst,
                       int* __restrict__ cursor, int* __restrict__ sortedE,
                       int* __restrict__ dstS, int E){
  int e = blockIdx.x*256 + threadIdx.x;
  if (e < E){
    int s = src[e];
    int p = atomicAdd(&cursor[s], 1);
    sortedE[p] = e;
    dstS[p] = dst[e];
  }
}

// ---------------- edge MLP via split-bf16 MFMA -> TRANSPOSED hidden ----
// hiddenT[h][e] (E-stride rows) so the fused conv kernel reads each h-row
// coalesced, once. 16-lane-contiguous 64B scalar-store runs.
__global__ __launch_bounds__(256,3) void k_edge_mlp_mfma(
    const u16* __restrict__ eaH, const u16* __restrict__ eaL,
    const u16* __restrict__ BT1h, const u16* __restrict__ BT1l,
    const float* __restrict__ nn1_b, float* __restrict__ hiddenT, int E)
{
  const int lane = threadIdx.x & 63;
  const int wave = threadIdx.x >> 6;
  const int row  = lane & 15;
  const int quad = lane >> 4;
  const int m0 = blockIdx.x*128 + (wave>>1)*64;
  const int n0 = (wave&1)*64;

  bf16x8 AH0[4], AH1[4], AL0[4], AL1[4];
  #pragma unroll
  for (int p=0;p<4;p++){
    int ar = min(m0 + p*16 + row, E-1);
    const u16* aH = eaH + (size_t)ar*64 + quad*8;
    const u16* aL = eaL + (size_t)ar*64 + quad*8;
    AH0[p] = *(const bf16x8*)(aH);
    AH1[p] = *(const bf16x8*)(aH + 32);
    AL0[p] = *(const bf16x8*)(aL);
    AL1[p] = *(const bf16x8*)(aL + 32);
  }
  #pragma unroll
  for (int tb=0;tb<4;tb++){
    const u16* bH = BT1h + (size_t)(n0 + tb*16 + row)*64 + quad*8;
    const u16* bL = BT1l + (size_t)(n0 + tb*16 + row)*64 + quad*8;
    bf16x8 bh0 = *(const bf16x8*)(bH);
    bf16x8 bh1 = *(const bf16x8*)(bH + 32);
    bf16x8 bl0 = *(const bf16x8*)(bL);
    bf16x8 bl1 = *(const bf16x8*)(bL + 32);
    float4 bias;
    {
      int nb = n0 + tb*16 + quad*4;
      bias.x = nn1_b[nb+0]; bias.y = nn1_b[nb+1];
      bias.z = nn1_b[nb+2]; bias.w = nn1_b[nb+3];
    }
    #pragma unroll
    for (int ta=0;ta<4;ta++){
      f32x4 a = {0.f,0.f,0.f,0.f};
      a = __builtin_amdgcn_mfma_f32_16x16x32_bf16(bh0, AH0[ta], a, 0,0,0);
      a = __builtin_amdgcn_mfma_f32_16x16x32_bf16(bh1, AH1[ta], a, 0,0,0);
      a = __builtin_amdgcn_mfma_f32_16x16x32_bf16(bl0, AH0[ta], a, 0,0,0);
      a = __builtin_amdgcn_mfma_f32_16x16x32_bf16(bl1, AH1[ta], a, 0,0,0);
      a = __builtin_amdgcn_mfma_f32_16x16x32_bf16(bh0, AL0[ta], a, 0,0,0);
      a = __builtin_amdgcn_mfma_f32_16x16x32_bf16(bh1, AL1[ta], a, 0,0,0);
      int m = m0 + ta*16 + row;
      if (m < E){
        int colb = n0 + tb*16 + quad*4;
        hiddenT[(size_t)(colb+0)*E + m] = fmaxf(a[0]+bias.x, 0.f);
        hiddenT[(size_t)(colb+1)*E + m] = fmaxf(a[1]+bias.y, 0.f);
        hiddenT[(size_t)(colb+2)*E + m] = fmaxf(a[2]+bias.z, 0.f);
        hiddenT[(size_t)(colb+3)*E + m] = fmaxf(a[3]+bias.w, 0.f);
      }
    }
  }
}

// ---------------- FUSED conv: Q-slab MFMA in LDS + edge accumulate --------------
// Eliminates the 160 MB Q write + 160 MB read per conv (4 dispatches @ ~2 TB/s
// logical were 60% of runtime; four optimization attempts never moved that rate).
// Block = 32 nodes (4 waves). Key fact: Q column-slab cb == hidden column cb.
// Loop 32 groups of 4 slabs: wave wv MFMA-computes slab 4g+wv (32x64, f32) into
// LDS; hiddenT rows 4g..4g+3 staged (coalesced, read once); each wave owns 8
// nodes -> per node 4 Q-regs reused across its edges; per-edge msg[ECAP][64]
// accumulates in LDS across groups; one atomicAdd per edge at the end.
// Chunk loop guarantees correctness for any degree distribution.
// LDS = 119 KB -> ONE workgroup/CU. launch_bounds min-waves/EU MUST be 1:
// (256,2) demands 2 wg/CU -> 80 KB LDS cap -> compile error (round-8 failure).
__global__ __launch_bounds__(256,1) void k_fused_conv(
    const u16* __restrict__ Ah, const u16* __restrict__ Al,
    const u16* __restrict__ BhT, const u16* __restrict__ BlT,
    const float* __restrict__ hiddenT, const float* __restrict__ bterm,
    const int* __restrict__ starts, const int* __restrict__ dstS,
    float* __restrict__ agg, int N, int E)
{
  __shared__ float Qs[4][32][68];     // 4 slabs x 32 nodes x 64(+4 pad) f32
  __shared__ float msg[ECAP][64];
  __shared__ float hst[4][ECAP];
  const int tid  = threadIdx.x;
  const int wv   = tid >> 6, lane = tid & 63;
  const int row  = lane & 15, quad = lane >> 4;
  const int n0g  = blockIdx.x * NPB;

  // A fragments: this block's 32 node rows (bf16 hi/lo), loaded once
  bf16x8 AH0[2], AH1[2], AL0[2], AL1[2];
  #pragma unroll
  for (int ta=0;ta<2;ta++){
    int ar = min(n0g + ta*16 + row, N-1);
    const u16* aH = Ah + (size_t)ar*64 + quad*8;
    const u16* aL = Al + (size_t)ar*64 + quad*8;
    AH0[ta] = *(const bf16x8*)(aH);
    AH1[ta] = *(const bf16x8*)(aH + 32);
    AL0[ta] = *(const bf16x8*)(aL);
    AL1[ta] = *(const bf16x8*)(aL + 32);
  }

  const int eblk0 = starts[n0g];
  const int eblk1 = starts[min(n0g + NPB, N)];

  for (int ce0 = eblk0; ce0 < eblk1; ce0 += ECAP){
    const int cnt = min(ECAP, eblk1 - ce0);
    const int ce1 = ce0 + cnt;
    // zero msg rows [0, cnt)
    for (int i = tid; i < cnt*64; i += 256) (&msg[0][0])[i] = 0.f;
    // per-wave owned-node edge ranges (clipped to chunk)
    int eS[8], eE[8];
    #pragma unroll
    for (int nn=0;nn<8;nn++){
      int n = n0g + wv*8 + nn;
      if (n < N){
        eS[nn] = max(starts[n], ce0);
        eE[nn] = min(starts[n+1], ce1);
      } else { eS[nn] = 0; eE[nn] = 0; }
    }
    // preload hidden rows for group 0
    float hr0[4], hr1[4];
    #pragma unroll
    for (int j=0;j<4;j++){
      hr0[j] = (tid < cnt)       ? hiddenT[(size_t)j*E + ce0 + tid]       : 0.f;
      hr1[j] = (tid + 256 < cnt) ? hiddenT[(size_t)j*E + ce0 + tid + 256] : 0.f;
    }
    __syncthreads();

    for (int g=0; g<32; ++g){
      // ---- compute Q slab cb = 4g+wv via split-bf16 MFMA (M=32, N=64, K=64)
      const int cb = g*4 + wv;
      const u16* Bh = BhT + ((size_t)(cb>>6))*262144 + (size_t)(cb&63)*4096;
      const u16* Bl = BlT + ((size_t)(cb>>6))*262144 + (size_t)(cb&63)*4096;
      f32x4 acc[2][4];
      #pragma unroll
      for (int ta=0;ta<2;ta++)
        #pragma unroll
        for (int tb=0;tb<4;tb++)
          acc[ta][tb] = (f32x4){0.f,0.f,0.f,0.f};
      #pragma unroll
      for (int tb=0;tb<4;tb++){
        const u16* bH = Bh + (size_t)(tb*16 + row)*64 + quad*8;
        const u16* bL = Bl + (size_t)(tb*16 + row)*64 + quad*8;
        bf16x8 bh0 = *(const bf16x8*)(bH);
        bf16x8 bh1 = *(const bf16x8*)(bH + 32);
        bf16x8 bl0 = *(const bf16x8*)(bL);
        bf16x8 bl1 = *(const bf16x8*)(bL + 32);
        #pragma unroll
        for (int ta=0;ta<2;ta++){
          f32x4 a = acc[ta][tb];
          a = __builtin_amdgcn_mfma_f32_16x16x32_bf16(bh0, AH0[ta], a, 0,0,0);
          a = __builtin_amdgcn_mfma_f32_16x16x32_bf16(bh1, AH1[ta], a, 0,0,0);
          a = __builtin_amdgcn_mfma_f32_16x16x32_bf16(bl0, AH0[ta], a, 0,0,0);
          a = __builtin_amdgcn_mfma_f32_16x16x32_bf16(bl1, AH1[ta], a, 0,0,0);
          a = __builtin_amdgcn_mfma_f32_16x16x32_bf16(bh0, AL0[ta], a, 0,0,0);
          a = __builtin_amdgcn_mfma_f32_16x16x32_bf16(bh1, AL1[ta], a, 0,0,0);
          acc[ta][tb] = a;
        }
      }
      // C layout (7x verified): value acc[ta][tb][reg] = Q[m=ta*16+row][o=tb*16+quad*4+reg]
      #pragma unroll
      for (int ta=0;ta<2;ta++)
        #pragma unroll
        for (int tb=0;tb<4;tb++)
          *(f32x4*)&Qs[wv][ta*16+row][tb*16+quad*4] = acc[ta][tb];
      // ---- stage this group's hidden values, prefetch next group's
      #pragma unroll
      for (int j=0;j<4;j++){
        if (tid < cnt)       hst[j][tid]     = hr0[j];
        if (tid + 256 < cnt) hst[j][tid+256] = hr1[j];
      }
      if (g < 31){
        const size_t hb = (size_t)(g+1)*4;
        #pragma unroll
        for (int j=0;j<4;j++){
          hr0[j] = (tid < cnt)       ? hiddenT[(hb+j)*E + ce0 + tid]       : 0.f;
          hr1[j] = (tid + 256 < cnt) ? hiddenT[(hb+j)*E + ce0 + tid + 256] : 0.f;
        }
      }
      __syncthreads();   // Qs + hst ready
      // ---- edge accumulate: wave's 8 owned nodes, Q in regs per node
      #pragma unroll
      for (int nn=0;nn<8;nn++){
        const int es = eS[nn], ee = eE[nn];
        if (es >= ee) continue;
        const int nl = wv*8 + nn;
        const float q0 = Qs[0][nl][lane];
        const float q1 = Qs[1][nl][lane];
        const float q2 = Qs[2][nl][lane];
        const float q3 = Qs[3][nl][lane];
        for (int e = es; e < ee; ++e){
          const int el = e - ce0;
          float m = msg[el][lane];
          m = fmaf(hst[0][el], q0, m);
          m = fmaf(hst[1][el], q1, m);
          m = fmaf(hst[2][el], q2, m);
          m = fmaf(hst[3][el], q3, m);
          msg[el][lane] = m;
        }
      }
      __syncthreads();   // before next group overwrites Qs/hst
    }
    // ---- flush: one atomicAdd per edge (bterm added once per edge)
    #pragma unroll
    for (int nn=0;nn<8;nn++){
      const int es = eS[nn], ee = eE[nn];
      if (es >= ee) continue;
      const int n = n0g + wv*8 + nn;
      const float bt = bterm[(size_t)n*64 + lane];
      for (int e = es; e < ee; ++e)
        atomicAdd(&agg[(size_t)dstS[e]*64 + lane], bt + msg[e-ce0][lane]);
    }
    __syncthreads();     // msg reused next chunk
  }
}

// ---------------- node update: 4 nodes/thread (weight loads amortized 4x) --------
__global__ __launch_bounds__(256) void k_node_update(const float* __restrict__ outOld,
    const float* __restrict__ agg, const float* __restrict__ deg,
    const float* __restrict__ rootT, const float* __restrict__ conv_b,
    const float* __restrict__ wihT, const float* __restrict__ whhT,
    const float* __restrict__ b_ih, const float* __restrict__ b_hh,
    const float* __restrict__ nn2_b,
    float* __restrict__ outNew, u16* __restrict__ outH, u16* __restrict__ outL,
    float* __restrict__ bterm, int N)
{
  __shared__ float hs[16][64];
  __shared__ float ms[16][64];
  const int w = threadIdx.x>>6, o = threadIdx.x&63;
  const int nb = blockIdx.x*16 + w*4;
  float h[4];
  #pragma unroll
  for (int j=0;j<4;j++){
    int n = nb+j;
    h[j] = (n<N) ? outOld[(size_t)n*64+o] : 0.f;
    hs[w*4+j][o] = h[j];
  }
  // per-wave LDS slice: in-wave ordering, no barrier
  float root[4] = {0.f,0.f,0.f,0.f};
  for (int i=0;i<64;i++){
    float rw = rootT[i*64+o];
    #pragma unroll
    for (int j=0;j<4;j++) root[j] = fmaf(hs[w*4+j][i], rw, root[j]);
  }
  float cb = conv_b[o];
  float m[4];
  #pragma unroll
  for (int j=0;j<4;j++){
    int n = nb+j;
    float d = (n<N) ? fmaxf(deg[n], 1.f) : 1.f;
    float a = (n<N) ? agg[(size_t)n*64+o]/d : 0.f;
    m[j] = fmaxf(a + root[j] + cb, 0.f);
    ms[w*4+j][o] = m[j];
  }
  float gir[4],giz[4],gin[4],ghr[4],ghz[4],ghn[4];
  float bir=b_ih[o], biz=b_ih[64+o], bin=b_ih[128+o];
  float bhr=b_hh[o], bhz=b_hh[64+o], bhn=b_hh[128+o];
  #pragma unroll
  for (int j=0;j<4;j++){
    gir[j]=bir; giz[j]=biz; gin[j]=bin;
    ghr[j]=bhr; ghz[j]=bhz; ghn[j]=bhn;
  }
  for (int i=0;i<64;i++){
    float wr=wihT[i*192+o], wz=wihT[i*192+64+o], wn=wihT[i*192+128+o];
    float vr=whhT[i*192+o], vz=whhT[i*192+64+o], vn=whhT[i*192+128+o];
    #pragma unroll
    for (int j=0;j<4;j++){
      float mi = ms[w*4+j][i], hi = hs[w*4+j][i];
      gir[j]=fmaf(mi,wr,gir[j]); giz[j]=fmaf(mi,wz,giz[j]); gin[j]=fmaf(mi,wn,gin[j]);
      ghr[j]=fmaf(hi,vr,ghr[j]); ghz[j]=fmaf(hi,vz,ghz[j]); ghn[j]=fmaf(hi,vn,ghn[j]);
    }
  }
  float v[4];
  #pragma unroll
  for (int j=0;j<4;j++){
    float r = sigmoidf_(gir[j]+ghr[j]);
    float z = sigmoidf_(giz[j]+ghz[j]);
    float nn = tanhf(gin[j] + r*ghn[j]);
    v[j] = (1.f-z)*nn + z*h[j];
    int n = nb+j;
    if (n<N){
      outNew[(size_t)n*64+o] = v[j];
      u16 hi16, lo16; split_bf(v[j], hi16, lo16);
      outH[(size_t)n*64+o] = hi16;
      outL[(size_t)n*64+o] = lo16;
    }
  }
  float bt[4] = {0.f,0.f,0.f,0.f};
  for (int i=0;i<64;i++){
    float wnb = nn2_b[i*64+o];
    #pragma unroll
    for (int j=0;j<4;j++) bt[j] = fmaf(__shfl(v[j], i, 64), wnb, bt[j]);
  }
  #pragma unroll
  for (int j=0;j<4;j++){
    int n = nb+j;
    if (n<N) bterm[(size_t)n*64+o] = bt[j];
  }
}

// ---------------- Set2Set (3 steps) + final MLP: LDS-staged, one block/graph -------
__global__ __launch_bounds__(256) void k_set2set(const float* __restrict__ out,
    const int* __restrict__ batch, int N,
    const float* __restrict__ lwihT, const float* __restrict__ lwhhT,
    const float* __restrict__ b_ih, const float* __restrict__ b_hh,
    const float* __restrict__ lin1T, const float* __restrict__ lin1_b,
    const float* __restrict__ lin2_w, const float* __restrict__ lin2_b,
    float* __restrict__ y)
{
  __shared__ float X[S2CAP][65];
  __shared__ float earr[S2CAP];
  __shared__ float qstar[128], hl[64], cl[64], g[256];
  __shared__ float rpart[4][64], spart[4], redm[4], zs[64];
  __shared__ int sb[2];
  const int tid = threadIdx.x;
  const int b = blockIdx.x;
  const int wid = tid>>6, lane = tid&63;
  if (tid < 128) qstar[tid] = 0.f;
  if (tid < 64){ hl[tid]=0.f; cl[tid]=0.f; }
  if (tid == 0){
    int lo=0, hi=N;
    while (lo<hi){ int mid=(lo+hi)>>1; if (batch[mid] < b) lo=mid+1; else hi=mid; }
    sb[0]=lo;
    int lo2=lo, hi2=N;
    while (lo2<hi2){ int mid=(lo2+hi2)>>1; if (batch[mid] < b+1) lo2=mid+1; else hi2=mid; }
    sb[1]=lo2;
  }
  __syncthreads();
  const int nlo = sb[0], nhi = sb[1], nn = nhi - nlo;
  const bool single = (nn <= S2CAP);
  if (single){
    for (int idx = tid; idx < nn*64; idx += 256){
      X[idx>>6][idx&63] = out[(size_t)(nlo + (idx>>6))*64 + (idx&63)];
    }
  }
  __syncthreads();

  for (int step=0; step<3; step++){
    float gs = b_ih[tid] + b_hh[tid];
    for (int j=0;j<128;j++) gs = fmaf(qstar[j], lwihT[j*256+tid], gs);
    for (int j=0;j<64;j++)  gs = fmaf(hl[j],    lwhhT[j*256+tid], gs);
    g[tid] = gs;
    __syncthreads();
    if (tid < 64){
      float ig = sigmoidf_(g[tid]);
      float fg = sigmoidf_(g[64+tid]);
      float gg = tanhf(g[128+tid]);
      float og = sigmoidf_(g[192+tid]);
      float c = fg*cl[tid] + ig*gg;
      cl[tid] = c;
      hl[tid] = og*tanhf(c);
    }
    __syncthreads();

    if (single){
      float lm = -INFINITY;
      for (int n = tid; n < nn; n += 256){
        float acc = 0.f;
        #pragma unroll 8
        for (int d=0; d<64; d++) acc = fmaf(X[n][d], hl[d], acc);
        earr[n] = acc;
        lm = fmaxf(lm, acc);
      }
      lm = fmaxf(lm, __shfl_xor(lm,1));  lm = fmaxf(lm, __shfl_xor(lm,2));
      lm = fmaxf(lm, __shfl_xor(lm,4));  lm = fmaxf(lm, __shfl_xor(lm,8));
      lm = fmaxf(lm, __shfl_xor(lm,16)); lm = fmaxf(lm, __shfl_xor(lm,32));
      if (lane==0) redm[wid] = lm;
      __syncthreads();
      if (tid==0) redm[0] = fmaxf(fmaxf(redm[0],redm[1]), fmaxf(redm[2],redm[3]));
      __syncthreads();
      const float gmax = redm[0];
      float ls = 0.f;
      for (int n = tid; n < nn; n += 256){
        float a = expf(earr[n] - gmax);
        earr[n] = a;
        ls += a;
      }
      ls += __shfl_xor(ls,1);  ls += __shfl_xor(ls,2);  ls += __shfl_xor(ls,4);
      ls += __shfl_xor(ls,8);  ls += __shfl_xor(ls,16); ls += __shfl_xor(ls,32);
      if (lane==0) spart[wid] = ls;
      __syncthreads();
      float racc = 0.f;
      for (int n = wid; n < nn; n += 4) racc = fmaf(earr[n], X[n][lane], racc);
      rpart[wid][lane] = racc;
      __syncthreads();
      if (tid < 64){
        float r = rpart[0][tid]+rpart[1][tid]+rpart[2][tid]+rpart[3][tid];
        float s = spart[0]+spart[1]+spart[2]+spart[3];
        qstar[tid] = hl[tid];
        qstar[64+tid] = (nn>0) ? r/s : 0.f;
      }
      __syncthreads();
    } else {
      float qv = hl[lane];
      float lm = -INFINITY;
      for (int n = nlo + wid; n < nhi; n += 4){
        float p = out[(size_t)n*64 + lane]*qv;
        p += __shfl_xor(p,1); p += __shfl_xor(p,2); p += __shfl_xor(p,4);
        p += __shfl_xor(p,8); p += __shfl_xor(p,16); p += __shfl_xor(p,32);
        lm = fmaxf(lm, p);
      }
      if (lane==0) redm[wid] = lm;
      __syncthreads();
      if (tid==0) redm[0] = fmaxf(fmaxf(redm[0],redm[1]), fmaxf(redm[2],redm[3]));
      __syncthreads();
      float gmax = redm[0];
      float sw = 0.f, racc = 0.f;
      for (int n = nlo + wid; n < nhi; n += 4){
        float ol = out[(size_t)n*64 + lane];
        float p = ol*qv;
        p += __shfl_xor(p,1); p += __shfl_xor(p,2); p += __shfl_xor(p,4);
        p += __shfl_xor(p,8); p += __shfl_xor(p,16); p += __shfl_xor(p,32);
        float a = expf(p - gmax);
        sw += a;
        racc = fmaf(a, ol, racc);
      }
      rpart[wid][lane] = racc;
      if (lane==0) spart[wid] = sw;
      __syncthreads();
      if (tid < 64){
        float r = rpart[0][tid]+rpart[1][tid]+rpart[2][tid]+rpart[3][tid];
        float s = spart[0]+spart[1]+spart[2]+spart[3];
        qstar[tid] = hl[tid];
        qstar[64+tid] = (nn>0) ? r/s : 0.f;
      }
      __syncthreads();
    }
  }
  if (tid < 64){
    float acc = lin1_b[tid];
    for (int j=0;j<128;j++) acc = fmaf(qstar[j], lin1T[j*64+tid], acc);
    zs[tid] = fmaxf(acc, 0.f);
  }
  __syncthreads();
  if (tid < 64){
    float v = zs[lane]*lin2_w[lane];
    v += __shfl_xor(v,1); v += __shfl_xor(v,2); v += __shfl_xor(v,4);
    v += __shfl_xor(v,8); v += __shfl_xor(v,16); v += __shfl_xor(v,32);
    if (lane==0) y[b] = v + lin2_b[0];
  }
}

extern "C" void kernel_launch(void* const* d_in, const int* in_sizes, int n_in,
                              void* d_out, int out_size, void* d_ws, size_t ws_size,
                              hipStream_t stream)
{
  const float* x      = (const float*)d_in[0];
  const float* eattr  = (const float*)d_in[1];
  const float* lin0_w = (const float*)d_in[2];
  const float* lin0_b = (const float*)d_in[3];
  const float* nn1_w  = (const float*)d_in[4];
  const float* nn1_b  = (const float*)d_in[5];
  const float* nn2_w  = (const float*)d_in[6];
  const float* nn2_b  = (const float*)d_in[7];
  const float* root_w = (const float*)d_in[8];
  const float* conv_b = (const float*)d_in[9];
  const float* gwih   = (const float*)d_in[10];
  const float* gwhh   = (const float*)d_in[11];
  const float* gbih   = (const float*)d_in[12];
  const float* gbhh   = (const float*)d_in[13];
  const float* lwih   = (const float*)d_in[14];
  const float* lwhh   = (const float*)d_in[15];
  const float* lbih   = (const float*)d_in[16];
  const float* lbhh   = (const float*)d_in[17];
  const float* lin1_w = (const float*)d_in[18];
  const float* lin1_b = (const float*)d_in[19];
  const float* lin2_w = (const float*)d_in[20];
  const float* lin2_b = (const float*)d_in[21];
  const int*   eidx   = (const int*)d_in[22];
  const int*   batch  = (const int*)d_in[23];

  const int N = in_sizes[0]/FN;
  const int E = in_sizes[1]/FE;
  const int* srcI = eidx;
  const int* dstI = eidx + E;

  char* w = (char*)d_ws;
  size_t off = 0;
  auto alloc = [&](size_t bytes)->char* {
    char* p = w + off;
    off = (off + bytes + 255) & ~(size_t)255;
    return p;
  };
  float* degw  = (float*)alloc((size_t)N*4);
  int*   scnt  = (int*)alloc((size_t)N*4);
  int*   starts= (int*)alloc((size_t)(N+1)*4);
  int*   cursor= (int*)alloc((size_t)N*4);
  int*   bsum  = (int*)alloc((size_t)256*4);
  int*   sortedE=(int*)alloc((size_t)E*4);
  int*   dstS  = (int*)alloc((size_t)E*4);
  float* outA  = (float*)alloc((size_t)N*64*4);
  float* outB  = (float*)alloc((size_t)N*64*4);
  u16*   outAH = (u16*)alloc((size_t)N*64*2);
  u16*   outAL = (u16*)alloc((size_t)N*64*2);
  u16*   outBH = (u16*)alloc((size_t)N*64*2);
  u16*   outBL = (u16*)alloc((size_t)N*64*2);
  float* agg   = (float*)alloc((size_t)N*64*4);
  float* bterm = (float*)alloc((size_t)N*64*4);
  float* hiddenT=(float*)alloc((size_t)E*128*4);   // TRANSPOSED: [h][e]
  u16*   eaH   = (u16*)alloc((size_t)E*64*2);
  u16*   eaL   = (u16*)alloc((size_t)E*64*2);
  u16*   B2hT  = (u16*)alloc((size_t)524288*2);
  u16*   B2lT  = (u16*)alloc((size_t)524288*2);
  u16*   BT1h  = (u16*)alloc((size_t)8192*2);
  u16*   BT1l  = (u16*)alloc((size_t)8192*2);
  float* lin0T = (float*)alloc((size_t)92*64*4);
  float* nn1T  = (float*)alloc((size_t)41*128*4);
  float* rootT = (float*)alloc((size_t)64*64*4);
  float* wihT  = (float*)alloc((size_t)64*192*4);
  float* whhT  = (float*)alloc((size_t)64*192*4);
  float* lwihT = (float*)alloc((size_t)128*256*4);
  float* lwhhT = (float*)alloc((size_t)64*256*4);
  float* lin1T = (float*)alloc((size_t)128*64*4);

  const int NB = (N+255)/256;

  hipMemsetAsync(degw, 0, (size_t)N*4, stream);
  hipMemsetAsync(scnt, 0, (size_t)N*4, stream);
  k_pack<<<(97152+255)/256, 256, 0, stream>>>(lin0_w, nn1_w, root_w, gwih, gwhh,
      lwih, lwhh, lin1_w, lin0T, nn1T, rootT, wihT, whhT, lwihT, lwhhT, lin1T);
  k_pack_b2<<<524288/256, 256, 0, stream>>>(nn2_w, B2hT, B2lT);
  k_pack_b1<<<8192/256, 256, 0, stream>>>(nn1_w, BT1h, BT1l);
  k_node_mlp<<<(N+15)/16, 256, 0, stream>>>(x, lin0T, lin0_b, nn2_b, outA, outAH, outAL, bterm, N);
  k_count<<<(E+255)/256, 256, 0, stream>>>(dstI, srcI, degw, scnt, E);
  k_scan1<<<NB, 256, 0, stream>>>(scnt, starts, bsum, N);
  k_scan2<<<1, 256, 0, stream>>>(bsum, NB);
  k_scan3<<<NB, 256, 0, stream>>>(starts, cursor, bsum, N, E);
  k_sort<<<(E+255)/256, 256, 0, stream>>>(srcI, dstI, cursor, sortedE, dstS, E);
  k_split_ea<<<((size_t)E*64+255)/256, 256, 0, stream>>>(eattr, sortedE, eaH, eaL, E);
  k_edge_mlp_mfma<<<(E+127)/128, 256, 0, stream>>>(eaH, eaL, BT1h, BT1l, nn1_b, hiddenT, E);

  float* cur = outA; float* nxt = outB;
  u16* curH = outAH; u16* curL = outAL;
  u16* nxtH = outBH; u16* nxtL = outBL;
  const int fusedG = (N + NPB - 1) / NPB;
  for (int conv=0; conv<2; conv++){
    hipMemsetAsync(agg, 0, (size_t)N*64*4, stream);
    k_fused_conv<<<fusedG, 256, 0, stream>>>(curH, curL, B2hT, B2lT, hiddenT,
        bterm, starts, dstS, agg, N, E);
    k_node_update<<<(N+15)/16, 256, 0, stream>>>(cur, agg, degw, rootT, conv_b,
        wihT, whhT, gbih, gbhh, nn2_b, nxt, nxtH, nxtL, bterm, N);
    float* t = cur; cur = nxt; nxt = t;
    u16* th = curH; curH = nxtH; nxtH = th;
    u16* tl = curL; curL = nxtL; nxtL = tl;
  }

  k_set2set<<<128, 256, 0, stream>>>(cur, batch, N, lwihT, lwhhT, lbih, lbhh,
      lin1T, lin1_b, lin2_w, lin2_b, (float*)d_out);
}

// Round 10
// 582.364 us; speedup vs baseline: 2.0537x; 2.0537x over previous
//
#include <hip/hip_runtime.h>
#include <hip/hip_bf16.h>
#include <math.h>

#define DD 64
#define HIDC 128
#define FN 92
#define FE 41
#define S2CAP 192

typedef unsigned short u16;
typedef short bf16x8 __attribute__((ext_vector_type(8)));
typedef float f32x4 __attribute__((ext_vector_type(4)));
typedef u16 u16x8 __attribute__((ext_vector_type(8)));

__device__ __forceinline__ float sigmoidf_(float x){ return 1.f/(1.f+expf(-x)); }

__device__ __forceinline__ u16 f2bf(float v){
  union { float f; unsigned u; } x; x.f = v;
  unsigned r = x.u + 0x7fff + ((x.u >> 16) & 1);
  return (u16)(r >> 16);
}
__device__ __forceinline__ float bf2f(u16 v){
  union { float f; unsigned u; } x; x.u = ((unsigned)v) << 16;
  return x.f;
}
__device__ __forceinline__ void split_bf(float v, u16& h, u16& l){
  h = f2bf(v); l = f2bf(v - bf2f(h));
}

// ---------------- pack/transpose small weights ----------------
__global__ void k_pack(const float* __restrict__ lin0_w, const float* __restrict__ nn1_w,
                       const float* __restrict__ root_w, const float* __restrict__ gwih,
                       const float* __restrict__ gwhh, const float* __restrict__ lwih,
                       const float* __restrict__ lwhh, const float* __restrict__ lin1_w,
                       float* __restrict__ lin0T, float* __restrict__ nn1T,
                       float* __restrict__ rootT, float* __restrict__ wihT,
                       float* __restrict__ whhT, float* __restrict__ lwihT,
                       float* __restrict__ lwhhT, float* __restrict__ lin1T)
{
  int idx = blockIdx.x*blockDim.x + threadIdx.x;
  if (idx < 92*64){ int k=idx/64, o=idx%64; lin0T[k*64+o] = lin0_w[o*92+k]; return; } idx -= 92*64;
  if (idx < 41*128){ int k=idx/128, h=idx%128; nn1T[k*128+h] = nn1_w[h*41+k]; return; } idx -= 41*128;
  if (idx < 64*64){ int i=idx/64, o=idx%64; rootT[i*64+o] = root_w[o*64+i]; return; } idx -= 64*64;
  if (idx < 64*192){ int i=idx/192, g=idx%192; wihT[i*192+g] = gwih[g*64+i]; return; } idx -= 64*192;
  if (idx < 64*192){ int i=idx/192, g=idx%192; whhT[i*192+g] = gwhh[g*64+i]; return; } idx -= 64*192;
  if (idx < 128*256){ int j=idx/256, t=idx%256; lwihT[j*256+t] = lwih[t*128+j]; return; } idx -= 128*256;
  if (idx < 64*256){ int j=idx/256, t=idx%256; lwhhT[j*256+t] = lwhh[t*64+j]; return; } idx -= 64*256;
  if (idx < 128*64){ int j=idx/64, t=idx%64; lin1T[j*64+t] = lin1_w[t*128+j]; return; }
}

// Split nn2_w into bf16 hi/lo, transposed for MFMA B-fragments:
// BT[c*262144 + (h*64+o)*64 + i] = nn2_w[(i*64+o)*128 + c*64 + h]   (c = 64-h chunk)
__global__ void k_pack_b2(const float* __restrict__ nn2_w,
                          u16* __restrict__ BhT, u16* __restrict__ BlT){
  int idx = blockIdx.x*256 + threadIdx.x;
  if (idx >= 524288) return;
  int i  = idx & 63;
  int ho = (idx >> 6) & 4095;
  int c  = idx >> 18;
  int h = ho >> 6, o = ho & 63;
  float v = nn2_w[(size_t)(i*64+o)*128 + c*64 + h];
  u16 hi, lo; split_bf(v, hi, lo);
  BhT[idx] = hi; BlT[idx] = lo;
}

// nn1_w [128,41] -> B-fragment layout [h][k] padded K=64, bf16 hi/lo
__global__ void k_pack_b1(const float* __restrict__ nn1_w,
                          u16* __restrict__ BT1h, u16* __restrict__ BT1l){
  int idx = blockIdx.x*256 + threadIdx.x;
  if (idx >= 8192) return;
  int h = idx >> 6, k = idx & 63;
  float v = (k < FE) ? nn1_w[(size_t)h*FE + k] : 0.f;
  u16 hi, lo; split_bf(v, hi, lo);
  BT1h[idx] = hi; BT1l[idx] = lo;
}

// gather ea rows into sorted order, split bf16 hi/lo, pad K 41->64
__global__ void k_split_ea(const float* __restrict__ ea, const int* __restrict__ sortedE,
                           u16* __restrict__ eaH, u16* __restrict__ eaL, int E){
  int idx = blockIdx.x*256 + threadIdx.x;
  if (idx >= E*64) return;
  int ew = idx >> 6, k = idx & 63;
  int e = sortedE[ew];
  float v = (k < FE) ? ea[(size_t)e*FE + k] : 0.f;
  u16 hi, lo; split_bf(v, hi, lo);
  eaH[idx] = hi; eaL[idx] = lo;
}

// ---------------- node MLP: 4 nodes/thread (weight loads amortized 4x) ----------
__global__ __launch_bounds__(256) void k_node_mlp(const float* __restrict__ x,
    const float* __restrict__ lin0T, const float* __restrict__ lin0_b,
    const float* __restrict__ nn2_b,
    float* __restrict__ out, u16* __restrict__ outH, u16* __restrict__ outL,
    float* __restrict__ bterm, int N)
{
  __shared__ float xs[16][FN];
  const int w = threadIdx.x>>6, o = threadIdx.x&63;
  const int nb = blockIdx.x*16 + w*4;
  for (int idx = o; idx < 4*FN; idx += 64){
    int j = idx/FN, k = idx%FN;
    int n = nb + j;
    xs[w*4+j][k] = (n<N) ? x[(size_t)n*FN + k] : 0.f;
  }
  // per-wave LDS slice: in-wave lgkmcnt ordering, no barrier
  float acc[4];
  float bv = lin0_b[o];
  #pragma unroll
  for (int j=0;j<4;j++) acc[j] = bv;
  for (int k=0;k<FN;k++){
    float lw = lin0T[k*64+o];
    #pragma unroll
    for (int j=0;j<4;j++) acc[j] = fmaf(xs[w*4+j][k], lw, acc[j]);
  }
  float v[4];
  #pragma unroll
  for (int j=0;j<4;j++){
    v[j] = fmaxf(acc[j], 0.f);
    int n = nb + j;
    if (n < N){
      out[(size_t)n*64+o] = v[j];
      u16 hi, lo; split_bf(v[j], hi, lo);
      outH[(size_t)n*64+o] = hi;
      outL[(size_t)n*64+o] = lo;
    }
  }
  float bt[4] = {0.f,0.f,0.f,0.f};
  for (int i=0;i<64;i++){
    float wnb = nn2_b[i*64+o];
    #pragma unroll
    for (int j=0;j<4;j++) bt[j] = fmaf(__shfl(v[j], i, 64), wnb, bt[j]);
  }
  #pragma unroll
  for (int j=0;j<4;j++){
    int n = nb + j;
    if (n < N) bterm[(size_t)n*64+o] = bt[j];
  }
}

// ---------------- degree + src histogram ----------------
__global__ void k_count(const int* __restrict__ dst, const int* __restrict__ src,
                        float* __restrict__ deg, int* __restrict__ scnt, int E){
  int e = blockIdx.x*blockDim.x + threadIdx.x;
  if (e < E){
    atomicAdd(&deg[dst[e]], 1.f);
    atomicAdd(&scnt[src[e]], 1);
  }
}

// ---------------- 3-kernel exclusive scan over scnt[N] ----------------
__global__ void k_scan1(const int* __restrict__ cnt, int* __restrict__ excl,
                        int* __restrict__ bsum, int N){
  __shared__ int buf[256];
  int i = blockIdx.x*256 + threadIdx.x;
  int v = (i<N) ? cnt[i] : 0;
  buf[threadIdx.x] = v;
  __syncthreads();
  #pragma unroll
  for (int off=1; off<256; off<<=1){
    int t = (threadIdx.x>=off) ? buf[threadIdx.x-off] : 0;
    __syncthreads();
    buf[threadIdx.x] += t;
    __syncthreads();
  }
  if (i<N) excl[i] = buf[threadIdx.x] - v;
  if (threadIdx.x==255) bsum[blockIdx.x] = buf[255];
}
__global__ void k_scan2(int* __restrict__ bsum, int nb){
  __shared__ int buf[256];
  int v = (threadIdx.x<nb) ? bsum[threadIdx.x] : 0;
  buf[threadIdx.x] = v;
  __syncthreads();
  #pragma unroll
  for (int off=1; off<256; off<<=1){
    int t = (threadIdx.x>=off) ? buf[threadIdx.x-off] : 0;
    __syncthreads();
    buf[threadIdx.x] += t;
    __syncthreads();
  }
  if (threadIdx.x<nb) bsum[threadIdx.x] = buf[threadIdx.x] - v;
}
__global__ void k_scan3(int* __restrict__ starts, int* __restrict__ cursor,
                        const int* __restrict__ bsum, int N, int E){
  int i = blockIdx.x*256 + threadIdx.x;
  if (i<N){
    int s = starts[i] + bsum[blockIdx.x];
    starts[i] = s;
    cursor[i] = s;
  }
  if (i==0) starts[N] = E;
}

// ---------------- scatter: sortedE grouped by src, + sorted dst array -------
__global__ void k_sort(const int* __restrict__ src, const int* __restrict__ dst,
                       int* __restrict__ cursor, int* __restrict__ sortedE,
                       int* __restrict__ dstS, int E){
  int e = blockIdx.x*256 + threadIdx.x;
  if (e < E){
    int s = src[e];
    int p = atomicAdd(&cursor[s], 1);
    sortedE[p] = e;
    dstS[p] = dst[e];
  }
}

// ---------------- edge MLP via split-bf16 MFMA, swapped operands, direct stores ----
__global__ __launch_bounds__(256,3) void k_edge_mlp_mfma(
    const u16* __restrict__ eaH, const u16* __restrict__ eaL,
    const u16* __restrict__ BT1h, const u16* __restrict__ BT1l,
    const float* __restrict__ nn1_b, float* __restrict__ hidden, int E)
{
  const int lane = threadIdx.x & 63;
  const int wave = threadIdx.x >> 6;
  const int row  = lane & 15;
  const int quad = lane >> 4;
  const int m0 = blockIdx.x*128 + (wave>>1)*64;
  const int n0 = (wave&1)*64;

  bf16x8 AH0[4], AH1[4], AL0[4], AL1[4];
  #pragma unroll
  for (int p=0;p<4;p++){
    int ar = min(m0 + p*16 + row, E-1);
    const u16* aH = eaH + (size_t)ar*64 + quad*8;
    const u16* aL = eaL + (size_t)ar*64 + quad*8;
    AH0[p] = *(const bf16x8*)(aH);
    AH1[p] = *(const bf16x8*)(aH + 32);
    AL0[p] = *(const bf16x8*)(aL);
    AL1[p] = *(const bf16x8*)(aL + 32);
  }
  #pragma unroll
  for (int tb=0;tb<4;tb++){
    const u16* bH = BT1h + (size_t)(n0 + tb*16 + row)*64 + quad*8;
    const u16* bL = BT1l + (size_t)(n0 + tb*16 + row)*64 + quad*8;
    bf16x8 bh0 = *(const bf16x8*)(bH);
    bf16x8 bh1 = *(const bf16x8*)(bH + 32);
    bf16x8 bl0 = *(const bf16x8*)(bL);
    bf16x8 bl1 = *(const bf16x8*)(bL + 32);
    float4 bias;
    {
      int nb = n0 + tb*16 + quad*4;
      bias.x = nn1_b[nb+0]; bias.y = nn1_b[nb+1];
      bias.z = nn1_b[nb+2]; bias.w = nn1_b[nb+3];
    }
    #pragma unroll
    for (int ta=0;ta<4;ta++){
      f32x4 a = {0.f,0.f,0.f,0.f};
      a = __builtin_amdgcn_mfma_f32_16x16x32_bf16(bh0, AH0[ta], a, 0,0,0);
      a = __builtin_amdgcn_mfma_f32_16x16x32_bf16(bh1, AH1[ta], a, 0,0,0);
      a = __builtin_amdgcn_mfma_f32_16x16x32_bf16(bl0, AH0[ta], a, 0,0,0);
      a = __builtin_amdgcn_mfma_f32_16x16x32_bf16(bl1, AH1[ta], a, 0,0,0);
      a = __builtin_amdgcn_mfma_f32_16x16x32_bf16(bh0, AL0[ta], a, 0,0,0);
      a = __builtin_amdgcn_mfma_f32_16x16x32_bf16(bh1, AL1[ta], a, 0,0,0);
      int m = m0 + ta*16 + row;
      if (m < E){
        float4 v;
        v.x = fmaxf(a[0]+bias.x, 0.f); v.y = fmaxf(a[1]+bias.y, 0.f);
        v.z = fmaxf(a[2]+bias.z, 0.f); v.w = fmaxf(a[3]+bias.w, 0.f);
        *(float4*)(hidden + (size_t)m*128 + n0 + tb*16 + quad*4) = v;
      }
    }
  }
}

// ---------------- Q GEMM via split-bf16 MFMA, swapped operands, bf16 output -------
// r2-proven config (best total 573 us): row-major Q [n][4096], chunked B, 64-row
// tiles, permuted intra-64 stores for full-64B-sector writes:
//   pos(o=(tb*16+quad*4+reg)) = (tb>>1)*32 + quad*8 + (tb&1)*4 + reg
__global__ __launch_bounds__(256,3) void k_qgemm_mfma(
    const u16* __restrict__ Ah, const u16* __restrict__ Al,
    const u16* __restrict__ BhT, const u16* __restrict__ BlT,
    u16* __restrict__ C, int M)
{
  const int lane = threadIdx.x & 63;
  const int wave = threadIdx.x >> 6;
  const int row  = lane & 15;
  const int quad = lane >> 4;
  const int m0 = blockIdx.y * 64;
  const int n0 = blockIdx.x * 256 + wave * 64;

  bf16x8 AH0[4], AH1[4], AL0[4], AL1[4];
  #pragma unroll
  for (int p=0;p<4;p++){
    int ar = min(m0 + p*16 + row, M-1);
    const u16* aH = Ah + (size_t)ar*64 + quad*8;
    const u16* aL = Al + (size_t)ar*64 + quad*8;
    AH0[p] = *(const bf16x8*)(aH);
    AH1[p] = *(const bf16x8*)(aH + 32);
    AL0[p] = *(const bf16x8*)(aL);
    AL1[p] = *(const bf16x8*)(aL + 32);
  }

  f32x4 acc[4][4];
  #pragma unroll
  for (int ta=0;ta<4;ta++)
    #pragma unroll
    for (int tb=0;tb<4;tb++)
      acc[ta][tb] = (f32x4){0.f,0.f,0.f,0.f};

  #pragma unroll
  for (int tb=0;tb<4;tb++){
    const u16* bH = BhT + (size_t)(n0 + tb*16 + row)*64 + quad*8;
    const u16* bL = BlT + (size_t)(n0 + tb*16 + row)*64 + quad*8;
    bf16x8 bh0 = *(const bf16x8*)(bH);
    bf16x8 bh1 = *(const bf16x8*)(bH + 32);
    bf16x8 bl0 = *(const bf16x8*)(bL);
    bf16x8 bl1 = *(const bf16x8*)(bL + 32);
    #pragma unroll
    for (int ta=0;ta<4;ta++){
      f32x4 a = acc[ta][tb];
      a = __builtin_amdgcn_mfma_f32_16x16x32_bf16(bh0, AH0[ta], a, 0,0,0);
      a = __builtin_amdgcn_mfma_f32_16x16x32_bf16(bh1, AH1[ta], a, 0,0,0);
      a = __builtin_amdgcn_mfma_f32_16x16x32_bf16(bl0, AH0[ta], a, 0,0,0);
      a = __builtin_amdgcn_mfma_f32_16x16x32_bf16(bl1, AH1[ta], a, 0,0,0);
      a = __builtin_amdgcn_mfma_f32_16x16x32_bf16(bh0, AL0[ta], a, 0,0,0);
      a = __builtin_amdgcn_mfma_f32_16x16x32_bf16(bh1, AL1[ta], a, 0,0,0);
      acc[ta][tb] = a;
    }
  }

  #pragma unroll
  for (int ta=0;ta<4;ta++){
    int m = m0 + ta*16 + row;
    if (m >= M) continue;
    u16* dst = C + (size_t)m*4096 + n0 + quad*8;
    #pragma unroll
    for (int p=0;p<2;p++){
      f32x4 aa = acc[ta][2*p];
      f32x4 ab = acc[ta][2*p+1];
      u16x8 v;
      v[0]=f2bf(aa[0]); v[1]=f2bf(aa[1]); v[2]=f2bf(aa[2]); v[3]=f2bf(aa[3]);
      v[4]=f2bf(ab[0]); v[5]=f2bf(ab[1]); v[6]=f2bf(ab[2]); v[7]=f2bf(ab[3]);
      *(u16x8*)(dst + p*32) = v;
    }
  }
}

// ---------------- edge gather: one wave per src node, Q row in registers ----------
// r2-proven: edges CSR-sorted by src; wave n loads Q[n] (8 KB -> 32 VGPRs) ONCE,
// applies to all deg(n) edges (Q traffic / mean-degree). Both passes atomicAdd
// into agg (pass 0 carries bterm).
template<int PASS>
__global__ __launch_bounds__(256) void k_edge_gather(const u16* __restrict__ Q,
    const float* __restrict__ hidden, int h0,
    const float* __restrict__ bterm, const int* __restrict__ starts,
    const int* __restrict__ dstS, float* __restrict__ agg, int N)
{
  __shared__ float hs[4][64];
  __shared__ float red[4][64];
  const int wv = threadIdx.x>>6, lane = threadIdx.x&63;
  const int n = blockIdx.x*4 + wv;
  if (n >= N) return;
  const int e0 = starts[n], e1 = starts[n+1];
  if (e0 >= e1) return;
  const int sg = lane>>4, oq = lane&15;
  // inverse of qgemm's intra-block store permutation: o = oq*4+r lives at posb(oq)+r
  const int posb = ((oq>>3)<<5) + ((oq&3)<<3) + (((oq>>2)&1)<<2);
  const u16* qp = Q + (size_t)n*4096 + sg*64 + posb;
  ushort4 qreg[16];
  #pragma unroll
  for (int j=0;j<16;j++) qreg[j] = *(const ushort4*)(qp + j*256);
  const float bt = (PASS==0) ? bterm[(size_t)n*64 + lane] : 0.f;

  float hvN = hidden[(size_t)e0*128 + h0 + lane];
  int   dN  = dstS[e0];
  for (int e=e0; e<e1; ++e){
    const float hv = hvN;
    const int   d  = dN;
    if (e+1 < e1){
      hvN = hidden[(size_t)(e+1)*128 + h0 + lane];
      dN  = dstS[e+1];
    }
    hs[wv][lane] = hv;
    // per-wave LDS only: in-wave lgkmcnt ordering suffices, no __syncthreads
    float a0=0.f,a1=0.f,a2=0.f,a3=0.f;
    #pragma unroll
    for (int j=0;j<16;j++){
      float h4 = hs[wv][j*4+sg];
      a0 = fmaf(h4, bf2f(qreg[j].x), a0);
      a1 = fmaf(h4, bf2f(qreg[j].y), a1);
      a2 = fmaf(h4, bf2f(qreg[j].z), a2);
      a3 = fmaf(h4, bf2f(qreg[j].w), a3);
    }
    a0 += __shfl_xor(a0,16); a0 += __shfl_xor(a0,32);
    a1 += __shfl_xor(a1,16); a1 += __shfl_xor(a1,32);
    a2 += __shfl_xor(a2,16); a2 += __shfl_xor(a2,32);
    a3 += __shfl_xor(a3,16); a3 += __shfl_xor(a3,32);
    if (lane < 16){
      float4 r; r.x=a0; r.y=a1; r.z=a2; r.w=a3;
      *(float4*)&red[wv][lane*4] = r;
    }
    // in-wave lgkmcnt ordering; no barrier
    atomicAdd(&agg[(size_t)d*64 + lane], bt + red[wv][lane]);
  }
}

// ---------------- node update: 4 nodes/thread (weight loads amortized 4x) --------
__global__ __launch_bounds__(256) void k_node_update(const float* __restrict__ outOld,
    const float* __restrict__ agg, const float* __restrict__ deg,
    const float* __restrict__ rootT, const float* __restrict__ conv_b,
    const float* __restrict__ wihT, const float* __restrict__ whhT,
    const float* __restrict__ b_ih, const float* __restrict__ b_hh,
    const float* __restrict__ nn2_b,
    float* __restrict__ outNew, u16* __restrict__ outH, u16* __restrict__ outL,
    float* __restrict__ bterm, int N)
{
  __shared__ float hs[16][64];
  __shared__ float ms[16][64];
  const int w = threadIdx.x>>6, o = threadIdx.x&63;
  const int nb = blockIdx.x*16 + w*4;
  float h[4];
  #pragma unroll
  for (int j=0;j<4;j++){
    int n = nb+j;
    h[j] = (n<N) ? outOld[(size_t)n*64+o] : 0.f;
    hs[w*4+j][o] = h[j];
  }
  // per-wave LDS slice: in-wave ordering, no barrier
  float root[4] = {0.f,0.f,0.f,0.f};
  for (int i=0;i<64;i++){
    float rw = rootT[i*64+o];
    #pragma unroll
    for (int j=0;j<4;j++) root[j] = fmaf(hs[w*4+j][i], rw, root[j]);
  }
  float cb = conv_b[o];
  float m[4];
  #pragma unroll
  for (int j=0;j<4;j++){
    int n = nb+j;
    float d = (n<N) ? fmaxf(deg[n], 1.f) : 1.f;
    float a = (n<N) ? agg[(size_t)n*64+o]/d : 0.f;
    m[j] = fmaxf(a + root[j] + cb, 0.f);
    ms[w*4+j][o] = m[j];
  }
  float gir[4],giz[4],gin[4],ghr[4],ghz[4],ghn[4];
  float bir=b_ih[o], biz=b_ih[64+o], bin=b_ih[128+o];
  float bhr=b_hh[o], bhz=b_hh[64+o], bhn=b_hh[128+o];
  #pragma unroll
  for (int j=0;j<4;j++){
    gir[j]=bir; giz[j]=biz; gin[j]=bin;
    ghr[j]=bhr; ghz[j]=bhz; ghn[j]=bhn;
  }
  for (int i=0;i<64;i++){
    float wr=wihT[i*192+o], wz=wihT[i*192+64+o], wn=wihT[i*192+128+o];
    float vr=whhT[i*192+o], vz=whhT[i*192+64+o], vn=whhT[i*192+128+o];
    #pragma unroll
    for (int j=0;j<4;j++){
      float mi = ms[w*4+j][i], hi = hs[w*4+j][i];
      gir[j]=fmaf(mi,wr,gir[j]); giz[j]=fmaf(mi,wz,giz[j]); gin[j]=fmaf(mi,wn,gin[j]);
      ghr[j]=fmaf(hi,vr,ghr[j]); ghz[j]=fmaf(hi,vz,ghz[j]); ghn[j]=fmaf(hi,vn,ghn[j]);
    }
  }
  float v[4];
  #pragma unroll
  for (int j=0;j<4;j++){
    float r = sigmoidf_(gir[j]+ghr[j]);
    float z = sigmoidf_(giz[j]+ghz[j]);
    float nn = tanhf(gin[j] + r*ghn[j]);
    v[j] = (1.f-z)*nn + z*h[j];
    int n = nb+j;
    if (n<N){
      outNew[(size_t)n*64+o] = v[j];
      u16 hi16, lo16; split_bf(v[j], hi16, lo16);
      outH[(size_t)n*64+o] = hi16;
      outL[(size_t)n*64+o] = lo16;
    }
  }
  float bt[4] = {0.f,0.f,0.f,0.f};
  for (int i=0;i<64;i++){
    float wnb = nn2_b[i*64+o];
    #pragma unroll
    for (int j=0;j<4;j++) bt[j] = fmaf(__shfl(v[j], i, 64), wnb, bt[j]);
  }
  #pragma unroll
  for (int j=0;j<4;j++){
    int n = nb+j;
    if (n<N) bterm[(size_t)n*64+o] = bt[j];
  }
}

// ---------------- Set2Set (3 steps) + final MLP: LDS-staged, one block/graph -------
__global__ __launch_bounds__(256) void k_set2set(const float* __restrict__ out,
    const int* __restrict__ batch, int N,
    const float* __restrict__ lwihT, const float* __restrict__ lwhhT,
    const float* __restrict__ b_ih, const float* __restrict__ b_hh,
    const float* __restrict__ lin1T, const float* __restrict__ lin1_b,
    const float* __restrict__ lin2_w, const float* __restrict__ lin2_b,
    float* __restrict__ y)
{
  __shared__ float X[S2CAP][65];
  __shared__ float earr[S2CAP];
  __shared__ float qstar[128], hl[64], cl[64], g[256];
  __shared__ float rpart[4][64], spart[4], redm[4], zs[64];
  __shared__ int sb[2];
  const int tid = threadIdx.x;
  const int b = blockIdx.x;
  const int wid = tid>>6, lane = tid&63;
  if (tid < 128) qstar[tid] = 0.f;
  if (tid < 64){ hl[tid]=0.f; cl[tid]=0.f; }
  if (tid == 0){
    int lo=0, hi=N;
    while (lo<hi){ int mid=(lo+hi)>>1; if (batch[mid] < b) lo=mid+1; else hi=mid; }
    sb[0]=lo;
    int lo2=lo, hi2=N;
    while (lo2<hi2){ int mid=(lo2+hi2)>>1; if (batch[mid] < b+1) lo2=mid+1; else hi2=mid; }
    sb[1]=lo2;
  }
  __syncthreads();
  const int nlo = sb[0], nhi = sb[1], nn = nhi - nlo;
  const bool single = (nn <= S2CAP);
  if (single){
    for (int idx = tid; idx < nn*64; idx += 256){
      X[idx>>6][idx&63] = out[(size_t)(nlo + (idx>>6))*64 + (idx&63)];
    }
  }
  __syncthreads();

  for (int step=0; step<3; step++){
    float gs = b_ih[tid] + b_hh[tid];
    for (int j=0;j<128;j++) gs = fmaf(qstar[j], lwihT[j*256+tid], gs);
    for (int j=0;j<64;j++)  gs = fmaf(hl[j],    lwhhT[j*256+tid], gs);
    g[tid] = gs;
    __syncthreads();
    if (tid < 64){
      float ig = sigmoidf_(g[tid]);
      float fg = sigmoidf_(g[64+tid]);
      float gg = tanhf(g[128+tid]);
      float og = sigmoidf_(g[192+tid]);
      float c = fg*cl[tid] + ig*gg;
      cl[tid] = c;
      hl[tid] = og*tanhf(c);
    }
    __syncthreads();

    if (single){
      float lm = -INFINITY;
      for (int n = tid; n < nn; n += 256){
        float acc = 0.f;
        #pragma unroll 8
        for (int d=0; d<64; d++) acc = fmaf(X[n][d], hl[d], acc);
        earr[n] = acc;
        lm = fmaxf(lm, acc);
      }
      lm = fmaxf(lm, __shfl_xor(lm,1));  lm = fmaxf(lm, __shfl_xor(lm,2));
      lm = fmaxf(lm, __shfl_xor(lm,4));  lm = fmaxf(lm, __shfl_xor(lm,8));
      lm = fmaxf(lm, __shfl_xor(lm,16)); lm = fmaxf(lm, __shfl_xor(lm,32));
      if (lane==0) redm[wid] = lm;
      __syncthreads();
      if (tid==0) redm[0] = fmaxf(fmaxf(redm[0],redm[1]), fmaxf(redm[2],redm[3]));
      __syncthreads();
      const float gmax = redm[0];
      float ls = 0.f;
      for (int n = tid; n < nn; n += 256){
        float a = expf(earr[n] - gmax);
        earr[n] = a;
        ls += a;
      }
      ls += __shfl_xor(ls,1);  ls += __shfl_xor(ls,2);  ls += __shfl_xor(ls,4);
      ls += __shfl_xor(ls,8);  ls += __shfl_xor(ls,16); ls += __shfl_xor(ls,32);
      if (lane==0) spart[wid] = ls;
      __syncthreads();
      float racc = 0.f;
      for (int n = wid; n < nn; n += 4) racc = fmaf(earr[n], X[n][lane], racc);
      rpart[wid][lane] = racc;
      __syncthreads();
      if (tid < 64){
        float r = rpart[0][tid]+rpart[1][tid]+rpart[2][tid]+rpart[3][tid];
        float s = spart[0]+spart[1]+spart[2]+spart[3];
        qstar[tid] = hl[tid];
        qstar[64+tid] = (nn>0) ? r/s : 0.f;
      }
      __syncthreads();
    } else {
      float qv = hl[lane];
      float lm = -INFINITY;
      for (int n = nlo + wid; n < nhi; n += 4){
        float p = out[(size_t)n*64 + lane]*qv;
        p += __shfl_xor(p,1); p += __shfl_xor(p,2); p += __shfl_xor(p,4);
        p += __shfl_xor(p,8); p += __shfl_xor(p,16); p += __shfl_xor(p,32);
        lm = fmaxf(lm, p);
      }
      if (lane==0) redm[wid] = lm;
      __syncthreads();
      if (tid==0) redm[0] = fmaxf(fmaxf(redm[0],redm[1]), fmaxf(redm[2],redm[3]));
      __syncthreads();
      float gmax = redm[0];
      float sw = 0.f, racc = 0.f;
      for (int n = nlo + wid; n < nhi; n += 4){
        float ol = out[(size_t)n*64 + lane];
        float p = ol*qv;
        p += __shfl_xor(p,1); p += __shfl_xor(p,2); p += __shfl_xor(p,4);
        p += __shfl_xor(p,8); p += __shfl_xor(p,16); p += __shfl_xor(p,32);
        float a = expf(p - gmax);
        sw += a;
        racc = fmaf(a, ol, racc);
      }
      rpart[wid][lane] = racc;
      if (lane==0) spart[wid] = sw;
      __syncthreads();
      if (tid < 64){
        float r = rpart[0][tid]+rpart[1][tid]+rpart[2][tid]+rpart[3][tid];
        float s = spart[0]+spart[1]+spart[2]+spart[3];
        qstar[tid] = hl[tid];
        qstar[64+tid] = (nn>0) ? r/s : 0.f;
      }
      __syncthreads();
    }
  }
  if (tid < 64){
    float acc = lin1_b[tid];
    for (int j=0;j<128;j++) acc = fmaf(qstar[j], lin1T[j*64+tid], acc);
    zs[tid] = fmaxf(acc, 0.f);
  }
  __syncthreads();
  if (tid < 64){
    float v = zs[lane]*lin2_w[lane];
    v += __shfl_xor(v,1); v += __shfl_xor(v,2); v += __shfl_xor(v,4);
    v += __shfl_xor(v,8); v += __shfl_xor(v,16); v += __shfl_xor(v,32);
    if (lane==0) y[b] = v + lin2_b[0];
  }
}

extern "C" void kernel_launch(void* const* d_in, const int* in_sizes, int n_in,
                              void* d_out, int out_size, void* d_ws, size_t ws_size,
                              hipStream_t stream)
{
  const float* x      = (const float*)d_in[0];
  const float* eattr  = (const float*)d_in[1];
  const float* lin0_w = (const float*)d_in[2];
  const float* lin0_b = (const float*)d_in[3];
  const float* nn1_w  = (const float*)d_in[4];
  const float* nn1_b  = (const float*)d_in[5];
  const float* nn2_w  = (const float*)d_in[6];
  const float* nn2_b  = (const float*)d_in[7];
  const float* root_w = (const float*)d_in[8];
  const float* conv_b = (const float*)d_in[9];
  const float* gwih   = (const float*)d_in[10];
  const float* gwhh   = (const float*)d_in[11];
  const float* gbih   = (const float*)d_in[12];
  const float* gbhh   = (const float*)d_in[13];
  const float* lwih   = (const float*)d_in[14];
  const float* lwhh   = (const float*)d_in[15];
  const float* lbih   = (const float*)d_in[16];
  const float* lbhh   = (const float*)d_in[17];
  const float* lin1_w = (const float*)d_in[18];
  const float* lin1_b = (const float*)d_in[19];
  const float* lin2_w = (const float*)d_in[20];
  const float* lin2_b = (const float*)d_in[21];
  const int*   eidx   = (const int*)d_in[22];
  const int*   batch  = (const int*)d_in[23];

  const int N = in_sizes[0]/FN;
  const int E = in_sizes[1]/FE;
  const int* srcI = eidx;
  const int* dstI = eidx + E;

  char* w = (char*)d_ws;
  size_t off = 0;
  auto alloc = [&](size_t bytes)->char* {
    char* p = w + off;
    off = (off + bytes + 255) & ~(size_t)255;
    return p;
  };
  float* degw  = (float*)alloc((size_t)N*4);
  int*   scnt  = (int*)alloc((size_t)N*4);
  int*   starts= (int*)alloc((size_t)(N+1)*4);
  int*   cursor= (int*)alloc((size_t)N*4);
  int*   bsum  = (int*)alloc((size_t)256*4);
  int*   sortedE=(int*)alloc((size_t)E*4);
  int*   dstS  = (int*)alloc((size_t)E*4);
  float* outA  = (float*)alloc((size_t)N*64*4);
  float* outB  = (float*)alloc((size_t)N*64*4);
  u16*   outAH = (u16*)alloc((size_t)N*64*2);
  u16*   outAL = (u16*)alloc((size_t)N*64*2);
  u16*   outBH = (u16*)alloc((size_t)N*64*2);
  u16*   outBL = (u16*)alloc((size_t)N*64*2);
  float* agg   = (float*)alloc((size_t)N*64*4);
  float* bterm = (float*)alloc((size_t)N*64*4);
  float* hidden= (float*)alloc((size_t)E*128*4);
  u16*   B2hT  = (u16*)alloc((size_t)524288*2);
  u16*   B2lT  = (u16*)alloc((size_t)524288*2);
  u16*   BT1h  = (u16*)alloc((size_t)8192*2);
  u16*   BT1l  = (u16*)alloc((size_t)8192*2);
  float* lin0T = (float*)alloc((size_t)92*64*4);
  float* nn1T  = (float*)alloc((size_t)41*128*4);
  float* rootT = (float*)alloc((size_t)64*64*4);
  float* wihT  = (float*)alloc((size_t)64*192*4);
  float* whhT  = (float*)alloc((size_t)64*192*4);
  float* lwihT = (float*)alloc((size_t)128*256*4);
  float* lwhhT = (float*)alloc((size_t)64*256*4);
  float* lin1T = (float*)alloc((size_t)128*64*4);
  u16*   Q     = (u16*)alloc((size_t)N*4096*2);   // one 64-h chunk, bf16: [n][h*64+perm(o)]
  // eaH/eaL overlay Q's buffer: consumed by k_edge_mlp_mfma before first qgemm write
  u16* eaH = (u16*)Q;
  u16* eaL = eaH + (size_t)E*64;

  const int NB = (N+255)/256;

  hipMemsetAsync(degw, 0, (size_t)N*4, stream);
  hipMemsetAsync(scnt, 0, (size_t)N*4, stream);
  k_pack<<<(97152+255)/256, 256, 0, stream>>>(lin0_w, nn1_w, root_w, gwih, gwhh,
      lwih, lwhh, lin1_w, lin0T, nn1T, rootT, wihT, whhT, lwihT, lwhhT, lin1T);
  k_pack_b2<<<524288/256, 256, 0, stream>>>(nn2_w, B2hT, B2lT);
  k_pack_b1<<<8192/256, 256, 0, stream>>>(nn1_w, BT1h, BT1l);
  k_node_mlp<<<(N+15)/16, 256, 0, stream>>>(x, lin0T, lin0_b, nn2_b, outA, outAH, outAL, bterm, N);
  k_count<<<(E+255)/256, 256, 0, stream>>>(dstI, srcI, degw, scnt, E);
  k_scan1<<<NB, 256, 0, stream>>>(scnt, starts, bsum, N);
  k_scan2<<<1, 256, 0, stream>>>(bsum, NB);
  k_scan3<<<NB, 256, 0, stream>>>(starts, cursor, bsum, N, E);
  k_sort<<<(E+255)/256, 256, 0, stream>>>(srcI, dstI, cursor, sortedE, dstS, E);
  k_split_ea<<<((size_t)E*64+255)/256, 256, 0, stream>>>(eattr, sortedE, eaH, eaL, E);
  k_edge_mlp_mfma<<<(E+127)/128, 256, 0, stream>>>(eaH, eaL, BT1h, BT1l, nn1_b, hidden, E);

  float* cur = outA; float* nxt = outB;
  u16* curH = outAH; u16* curL = outAL;
  u16* nxtH = outBH; u16* nxtL = outBL;
  const dim3 qgrid(16, (N+63)/64);
  const int gatherG = (N+3)/4;
  for (int conv=0; conv<2; conv++){
    hipMemsetAsync(agg, 0, (size_t)N*64*4, stream);
    // chunk 0 (h in [0,64)) -- adds bterm once per edge
    k_qgemm_mfma<<<qgrid, 256, 0, stream>>>(curH, curL, B2hT, B2lT, Q, N);
    k_edge_gather<0><<<gatherG, 256, 0, stream>>>(Q, hidden, 0, bterm, starts, dstS, agg, N);
    // chunk 1 (h in [64,128))
    k_qgemm_mfma<<<qgrid, 256, 0, stream>>>(curH, curL, B2hT + 262144, B2lT + 262144, Q, N);
    k_edge_gather<1><<<gatherG, 256, 0, stream>>>(Q, hidden, 64, bterm, starts, dstS, agg, N);
    k_node_update<<<(N+15)/16, 256, 0, stream>>>(cur, agg, degw, rootT, conv_b,
        wihT, whhT, gbih, gbhh, nn2_b, nxt, nxtH, nxtL, bterm, N);
    float* t = cur; cur = nxt; nxt = t;
    u16* th = curH; curH = nxtH; nxtH = th;
    u16* tl = curL; curL = nxtL; nxtL = tl;
  }

  k_set2set<<<128, 256, 0, stream>>>(cur, batch, N, lwihT, lwhhT, lbih, lbhh,
      lin1T, lin1_b, lin2_w, lin2_b, (float*)d_out);
}